// Round 3
// baseline (513.689 us; speedup 1.0000x reference)
//
#include <hip/hip_runtime.h>

#define NN 20000
#define DEG 16
#define HDIM 128
#define GDIM 512

typedef __attribute__((ext_vector_type(8))) short bf16x8;
typedef __attribute__((ext_vector_type(4))) float f32x4;
typedef __attribute__((ext_vector_type(2))) unsigned u32x2;
typedef unsigned long long ull;

#define L2E  1.4426950408889634f
#define L2E2 2.8853900817779268f

__device__ __forceinline__ f32x4 mfma16(bf16x8 a, bf16x8 b, f32x4 c) {
    return __builtin_amdgcn_mfma_f32_16x16x32_bf16(a, b, c, 0, 0, 0);
}

__device__ __forceinline__ unsigned short f2bf(float f) {
    unsigned u = __builtin_bit_cast(unsigned, f);
    u += 0x7FFFu + ((u >> 16) & 1u);
    return (unsigned short)(u >> 16);
}

__device__ __forceinline__ unsigned cvtpk(float lo, float hi) {
    unsigned r;
    asm("v_cvt_pk_bf16_f32 %0, %1, %2" : "=v"(r) : "v"(lo), "v"(hi));
    return r;
}

__device__ __forceinline__ float bfhi(unsigned u) {     // high16 -> f32
    return __builtin_bit_cast(float, u & 0xFFFF0000u);
}
__device__ __forceinline__ float bflo(unsigned u) {     // low16 -> f32
    return __builtin_bit_cast(float, u << 16);
}

__device__ __forceinline__ void barrier_lgkm() {
    asm volatile("s_waitcnt lgkmcnt(0)\ns_barrier" ::: "memory");
}

__device__ __forceinline__ float sig_pre(float x) {     // x pre-scaled by log2e
    return __builtin_amdgcn_rcpf(1.f + __builtin_amdgcn_exp2f(-x));
}
__device__ __forceinline__ float tanh_pre2(float x2) {  // x2 pre-scaled by 2*log2e
    return 1.f - 2.f * __builtin_amdgcn_rcpf(__builtin_amdgcn_exp2f(x2) + 1.f);
}

// ---------------- weight convert + combined bias ----------------------------
struct CvtArgs {
    const float *wih[3], *whh[3], *wl[3], *wr[3], *bih[3], *bhh[3];
    unsigned short *dih[3], *dhh[3], *dl[3], *dr[3];
    float *dbias[3];
};

__global__ __launch_bounds__(256) void cvt_kernel(CvtArgs a) {
    int l = blockIdx.x / 642, b = blockIdx.x % 642, t = threadIdx.x;
    if (b < 256) {                       // w_ih [512,128]
        int i = b * 256 + t;
        float s = ((i >> 14) == 2) ? L2E2 : L2E;
        a.dih[l][i] = f2bf(a.wih[l][i] * s);
    } else if (b < 512) {                // w_hh [512,128]
        int i = (b - 256) * 256 + t;
        float s = ((i >> 14) == 2) ? L2E2 : L2E;
        a.dhh[l][i] = f2bf(a.whh[l][i] * s);
    } else if (b < 576) {                // w_l [128,128]
        int i = (b - 512) * 256 + t;
        a.dl[l][i] = f2bf(a.wl[l][i]);
    } else if (b < 640) {                // w_r [128,128]
        int i = (b - 576) * 256 + t;
        a.dr[l][i] = f2bf(a.wr[l][i]);
    } else {                             // combined scaled bias [512] f32
        int i = (b - 640) * 256 + t;
        float s = ((i >> 7) == 2) ? L2E2 : L2E;
        a.dbias[l][i] = (a.bih[l][i] + a.bhh[l][i]) * s;
    }
}

// ---- phase A (shared): Xih^T tile = wih . htile^T, packed bf16 out ---------
// wave wv = gate; D rows = gate-dims, cols = nodes (cl).
__device__ __forceinline__ void phaseA(const unsigned short (*htile)[136],
        const unsigned short* __restrict__ wih, const float* __restrict__ biasc,
        unsigned short* __restrict__ xihb, int mbase, int cl, int qh, int k8, int wv) {
    bf16x8 hb[4];
#pragma unroll
    for (int kt = 0; kt < 4; ++kt)
        hb[kt] = *(const bf16x8*)(&htile[cl][kt * 32 + k8]);
#pragma unroll
    for (int dt = 0; dt < 8; ++dt) {
        f32x4 a2 = {0.f, 0.f, 0.f, 0.f};
        const int row = wv * 128 + dt * 16 + cl;
#pragma unroll
        for (int kt = 0; kt < 4; ++kt)
            a2 = mfma16(*(const bf16x8*)(wih + row * HDIM + kt * 32 + k8), hb[kt], a2);
        const int d0 = wv * 128 + dt * 16 + qh * 4;
        f32x4 bv = *(const f32x4*)(biasc + d0);
        u32x2 pk;
        pk[0] = cvtpk(a2[0] + bv[0], a2[1] + bv[1]);
        pk[1] = cvtpk(a2[2] + bv[2], a2[3] + bv[3]);
        *(u32x2*)(xihb + (size_t)(mbase + cl) * GDIM + d0) = pk;
    }
}

// ---- gemmA0: build h0 = concat(x, emb[type]) (bf16) + Xih layer 0 ----------
__global__ __launch_bounds__(256) void gemmA0_kernel(
        const float* __restrict__ x, const int* __restrict__ types,
        const float* __restrict__ emb, const unsigned short* __restrict__ wih,
        const float* __restrict__ biasc, unsigned short* __restrict__ h0,
        unsigned short* __restrict__ xihb) {
    __shared__ unsigned short htile[16][136];
    const int lane = threadIdx.x & 63, wv = threadIdx.x >> 6;
    const int cl = lane & 15, qh = lane >> 4, k8 = qh * 8;
    const int mbase = blockIdx.x * 16;

    const int row = threadIdx.x >> 4, c0 = (threadIdx.x & 15) * 8;
    f32x4 u0, u1;
    if (c0 < 96) {
        u0 = *(const f32x4*)(x + (size_t)(mbase + row) * 96 + c0);
        u1 = *(const f32x4*)(x + (size_t)(mbase + row) * 96 + c0 + 4);
    } else {
        int ty = types[mbase + row];
        u0 = *(const f32x4*)(emb + ty * 32 + (c0 - 96));
        u1 = *(const f32x4*)(emb + ty * 32 + (c0 - 96) + 4);
    }
    u32x2 pa, pb;
    pa[0] = cvtpk(u0[0], u0[1]); pa[1] = cvtpk(u0[2], u0[3]);
    pb[0] = cvtpk(u1[0], u1[1]); pb[1] = cvtpk(u1[2], u1[3]);
    *(u32x2*)(&htile[row][c0]) = pa;
    *(u32x2*)(&htile[row][c0 + 4]) = pb;
    *(u32x2*)(h0 + (size_t)(mbase + row) * HDIM + c0) = pa;
    *(u32x2*)(h0 + (size_t)(mbase + row) * HDIM + c0 + 4) = pb;
    __syncthreads();

    phaseA(htile, wih, biasc, xihb, mbase, cl, qh, k8, wv);
}

// ---------------- fused per-node LSTM (swapped operands) --------------------
// 512 threads / 8 waves, 16 nodes per block. Thread owns node=cl, gate-dims
// wv*16+qh*4..+4 of all 4 gates. Depth-2 gather prefetch, lgkm-only barrier.
__global__ __launch_bounds__(512, 4) void lstm_kernel(
        const unsigned short* __restrict__ xihb, const unsigned short* __restrict__ whh,
        const int* __restrict__ esrc, unsigned short* __restrict__ agg) {
    __shared__ unsigned short hbuf[2][16][136];
    __shared__ unsigned srcs[256];                 // src row byte offset (s<<10)

    const int tid = threadIdx.x;
    const int lane = tid & 63, wv = tid >> 6;
    const int cl = lane & 15, qh = lane >> 4, k8 = qh * 8;
    const int base = blockIdx.x * 16;
    const unsigned dimoff = (unsigned)(wv * 32 + qh * 8);

    if (tid < 256) srcs[tid] = ((unsigned)esrc[base * DEG + tid]) << 10;

    bf16x8 bfr[4][4];                              // whh fragments [ktile][gate]
#pragma unroll
    for (int kt = 0; kt < 4; ++kt)
#pragma unroll
        for (int g = 0; g < 4; ++g)
            bfr[kt][g] = *(const bf16x8*)(whh + (g * 128 + wv * 16 + cl) * HDIM + kt * 32 + k8);
    __syncthreads();

    const char* xb = (const char*)xihb;
    float c[4] = {};
    ull xrA[4], xrB[4];
    unsigned pk0, pk1;

    auto gath = [&](int t, ull* xr) {
        unsigned off = srcs[cl * 16 + t] | dimoff;
        const char* p = xb + off;
        xr[0] = *(const ull*)(p);
        xr[1] = *(const ull*)(p + 256);
        xr[2] = *(const ull*)(p + 512);
        xr[3] = *(const ull*)(p + 768);
    };
    gath(0, xrA);
    gath(1, xrB);

    auto step = [&](int t, ull* xu) {
        f32x4 acc[4];
#pragma unroll
        for (int g = 0; g < 4; ++g) {
            unsigned lo = (unsigned)xu[g], hi = (unsigned)(xu[g] >> 32);
            acc[g][0] = bflo(lo); acc[g][1] = bfhi(lo);
            acc[g][2] = bflo(hi); acc[g][3] = bfhi(hi);
        }
        if (t < 14) gath(t + 2, xu);               // depth-2 prefetch
        if (t > 0) {
            const int rb = (t + 1) & 1;
            bf16x8 a[4];
#pragma unroll
            for (int kt = 0; kt < 4; ++kt)
                a[kt] = *(const bf16x8*)(&hbuf[rb][cl][kt * 32 + k8]);
#pragma unroll
            for (int g = 0; g < 4; ++g)
#pragma unroll
                for (int kt = 0; kt < 4; ++kt)
                    acc[g] = mfma16(bfr[kt][g], a[kt], acc[g]);
        }
        float hv[4];
#pragma unroll
        for (int r = 0; r < 4; ++r) {
            float is = sig_pre(acc[0][r]);
            float fs = sig_pre(acc[1][r]);
            float gt = tanh_pre2(acc[2][r]);
            float os = sig_pre(acc[3][r]);
            float cc = fs * c[r] + is * gt;
            c[r] = cc;
            hv[r] = os * tanh_pre2(cc * L2E2);
        }
        pk0 = cvtpk(hv[0], hv[1]);
        pk1 = cvtpk(hv[2], hv[3]);
        const int wb = t & 1;
        u32x2 pk; pk[0] = pk0; pk[1] = pk1;
        *(u32x2*)(&hbuf[wb][cl][wv * 16 + qh * 4]) = pk;
        barrier_lgkm();
    };

    for (int t = 0; t < 16; t += 2) { step(t, xrA); step(t + 1, xrB); }

    u32x2 pk; pk[0] = pk0; pk[1] = pk1;
    *(u32x2*)(agg + (size_t)(base + cl) * HDIM + wv * 16 + qh * 4) = pk;
}

// ---- gemmCA: h_next = relu(agg.wl^T + h.wr^T + bl), then Xih next layer ----
__global__ __launch_bounds__(256) void gemmCA_kernel(
        const unsigned short* __restrict__ agg, const unsigned short* __restrict__ hcur,
        const unsigned short* __restrict__ wl, const unsigned short* __restrict__ wr,
        const float* __restrict__ bl, const unsigned short* __restrict__ wih,
        const float* __restrict__ biasc, unsigned short* __restrict__ hnext,
        unsigned short* __restrict__ xihb) {
    __shared__ unsigned short htile[16][136];
    const int lane = threadIdx.x & 63, wv = threadIdx.x >> 6;
    const int cl = lane & 15, qh = lane >> 4, k8 = qh * 8;
    const int mbase = blockIdx.x * 16;

    bf16x8 bA[4], bH[4];
#pragma unroll
    for (int kt = 0; kt < 4; ++kt) {
        bA[kt] = *(const bf16x8*)(agg  + (size_t)(mbase + cl) * HDIM + kt * 32 + k8);
        bH[kt] = *(const bf16x8*)(hcur + (size_t)(mbase + cl) * HDIM + kt * 32 + k8);
    }
#pragma unroll
    for (int dt = 0; dt < 2; ++dt) {
        f32x4 acc = {0.f, 0.f, 0.f, 0.f};
        const int row = wv * 32 + dt * 16 + cl;
#pragma unroll
        for (int kt = 0; kt < 4; ++kt)
            acc = mfma16(*(const bf16x8*)(wl + row * HDIM + kt * 32 + k8), bA[kt], acc);
#pragma unroll
        for (int kt = 0; kt < 4; ++kt)
            acc = mfma16(*(const bf16x8*)(wr + row * HDIM + kt * 32 + k8), bH[kt], acc);
        const int d0 = wv * 32 + dt * 16 + qh * 4;
        f32x4 bv = *(const f32x4*)(bl + d0);
        u32x2 pk;
        pk[0] = cvtpk(fmaxf(acc[0] + bv[0], 0.f), fmaxf(acc[1] + bv[1], 0.f));
        pk[1] = cvtpk(fmaxf(acc[2] + bv[2], 0.f), fmaxf(acc[3] + bv[3], 0.f));
        *(u32x2*)(hnext + (size_t)(mbase + cl) * HDIM + d0) = pk;
        *(u32x2*)(&htile[cl][d0]) = pk;
    }
    __syncthreads();

    phaseA(htile, wih, biasc, xihb, mbase, cl, qh, k8, wv);
}

// ---- gemmCfinal: out = agg.wl^T + h.wr^T + bl (f32) ------------------------
__global__ __launch_bounds__(256) void gemmCF_kernel(
        const unsigned short* __restrict__ agg, const unsigned short* __restrict__ hcur,
        const unsigned short* __restrict__ wl, const unsigned short* __restrict__ wr,
        const float* __restrict__ bl, float* __restrict__ fout) {
    const int lane = threadIdx.x & 63, wv = threadIdx.x >> 6;
    const int cl = lane & 15, qh = lane >> 4, k8 = qh * 8;
    const int mbase = blockIdx.x * 16;

    bf16x8 bA[4], bH[4];
#pragma unroll
    for (int kt = 0; kt < 4; ++kt) {
        bA[kt] = *(const bf16x8*)(agg  + (size_t)(mbase + cl) * HDIM + kt * 32 + k8);
        bH[kt] = *(const bf16x8*)(hcur + (size_t)(mbase + cl) * HDIM + kt * 32 + k8);
    }
#pragma unroll
    for (int dt = 0; dt < 2; ++dt) {
        f32x4 acc = {0.f, 0.f, 0.f, 0.f};
        const int row = wv * 32 + dt * 16 + cl;
#pragma unroll
        for (int kt = 0; kt < 4; ++kt)
            acc = mfma16(*(const bf16x8*)(wl + row * HDIM + kt * 32 + k8), bA[kt], acc);
#pragma unroll
        for (int kt = 0; kt < 4; ++kt)
            acc = mfma16(*(const bf16x8*)(wr + row * HDIM + kt * 32 + k8), bH[kt], acc);
        const int d0 = wv * 32 + dt * 16 + qh * 4;
        f32x4 bv = *(const f32x4*)(bl + d0);
        f32x4 v;
#pragma unroll
        for (int r = 0; r < 4; ++r) v[r] = acc[r] + bv[r];
        *(f32x4*)(fout + (size_t)(mbase + cl) * HDIM + d0) = v;
    }
}

// ---------------- host ------------------------------------------------------
extern "C" void kernel_launch(void* const* d_in, const int* in_sizes, int n_in,
                              void* d_out, int out_size, void* d_ws, size_t ws_size,
                              hipStream_t stream) {
    (void)in_sizes; (void)n_in; (void)out_size; (void)ws_size;

    const float* x     = (const float*)d_in[0];
    const int*   types = (const int*)d_in[1];
    const int*   esrc  = (const int*)d_in[2];
    const float* emb   = (const float*)d_in[4];

    char* ws = (char*)d_ws;
    unsigned short* hA   = (unsigned short*)ws; ws += (size_t)NN * HDIM * 2;
    unsigned short* hB   = (unsigned short*)ws; ws += (size_t)NN * HDIM * 2;
    unsigned short* agg  = (unsigned short*)ws; ws += (size_t)NN * HDIM * 2;
    unsigned short* xihb = (unsigned short*)ws; ws += (size_t)NN * GDIM * 2;
    unsigned short* wbf  = (unsigned short*)ws; ws += (size_t)3 * 163840 * 2;
    float*          bc   = (float*)ws;          // 3 x 512 f32

    unsigned short *wihb[3], *whhb[3], *wlb[3], *wrb[3];
    float* bcl[3];
    CvtArgs ca;
    for (int l = 0; l < 3; ++l) {
        unsigned short* lb = wbf + (size_t)l * 163840;
        wihb[l] = lb;
        whhb[l] = lb + 65536;
        wlb[l]  = lb + 131072;
        wrb[l]  = lb + 147456;
        bcl[l]  = bc + l * 512;
        ca.wih[l] = (const float*)d_in[5 + 7 * l + 0];
        ca.whh[l] = (const float*)d_in[5 + 7 * l + 1];
        ca.bih[l] = (const float*)d_in[5 + 7 * l + 2];
        ca.bhh[l] = (const float*)d_in[5 + 7 * l + 3];
        ca.wl[l]  = (const float*)d_in[5 + 7 * l + 4];
        ca.wr[l]  = (const float*)d_in[5 + 7 * l + 6];
        ca.dih[l] = wihb[l]; ca.dhh[l] = whhb[l]; ca.dl[l] = wlb[l]; ca.dr[l] = wrb[l];
        ca.dbias[l] = bcl[l];
    }
    cvt_kernel<<<1926, 256, 0, stream>>>(ca);

    gemmA0_kernel<<<NN / 16, 256, 0, stream>>>(x, types, emb, wihb[0], bcl[0], hA, xihb);

    unsigned short* hc = hA;
    unsigned short* hn = hB;
    for (int l = 0; l < 3; ++l) {
        const float* bl = (const float*)d_in[5 + 7 * l + 5];
        lstm_kernel<<<NN / 16, 512, 0, stream>>>(xihb, whhb[l], esrc, agg);
        if (l < 2) {
            gemmCA_kernel<<<NN / 16, 256, 0, stream>>>(
                agg, hc, wlb[l], wrb[l], bl, wihb[l + 1], bcl[l + 1], hn, xihb);
            unsigned short* t = hc; hc = hn; hn = t;
        } else {
            gemmCF_kernel<<<NN / 16, 256, 0, stream>>>(
                agg, hc, wlb[l], wrb[l], bl, (float*)d_out);
        }
    }
}

// Round 4
// 326.402 us; speedup vs baseline: 1.5738x; 1.5738x over previous
//
#include <hip/hip_runtime.h>

#define NN 20000
#define DEG 16
#define HDIM 128
#define GDIM 512

typedef __attribute__((ext_vector_type(8))) short bf16x8;
typedef __attribute__((ext_vector_type(4))) float f32x4;
typedef __attribute__((ext_vector_type(2))) unsigned u32x2;
typedef __attribute__((ext_vector_type(4))) unsigned u32x4;
typedef unsigned long long ull;

#define L2E  1.4426950408889634f
#define L2E2 2.8853900817779268f

__device__ __forceinline__ f32x4 mfma16(bf16x8 a, bf16x8 b, f32x4 c) {
    return __builtin_amdgcn_mfma_f32_16x16x32_bf16(a, b, c, 0, 0, 0);
}

__device__ __forceinline__ unsigned short f2bf(float f) {
    unsigned u = __builtin_bit_cast(unsigned, f);
    u += 0x7FFFu + ((u >> 16) & 1u);
    return (unsigned short)(u >> 16);
}

__device__ __forceinline__ unsigned cvtpk(float lo, float hi) {
    unsigned r;
    asm("v_cvt_pk_bf16_f32 %0, %1, %2" : "=v"(r) : "v"(lo), "v"(hi));
    return r;
}

__device__ __forceinline__ float bfhi(unsigned u) { return __builtin_bit_cast(float, u & 0xFFFF0000u); }
__device__ __forceinline__ float bflo(unsigned u) { return __builtin_bit_cast(float, u << 16); }

__device__ __forceinline__ void barrier_lgkm() {
    asm volatile("s_waitcnt lgkmcnt(0)\ns_barrier" ::: "memory");
}

__device__ __forceinline__ float sig_pre(float x) {     // x pre-scaled by log2e
    return __builtin_amdgcn_rcpf(1.f + __builtin_amdgcn_exp2f(-x));
}
__device__ __forceinline__ float tanh_pre2(float x2) {  // x2 pre-scaled by 2*log2e
    return 1.f - 2.f * __builtin_amdgcn_rcpf(__builtin_amdgcn_exp2f(x2) + 1.f);
}

// ---------------- weight convert + combined bias ----------------------------
struct CvtArgs {
    const float *wih[3], *whh[3], *wl[3], *wr[3], *bih[3], *bhh[3];
    unsigned short *dih[3], *dhh[3], *dl[3], *dr[3];
    float *dbias[3];
};

__global__ __launch_bounds__(256) void cvt_kernel(CvtArgs a) {
    int l = blockIdx.x / 642, b = blockIdx.x % 642, t = threadIdx.x;
    if (b < 256) {                       // w_ih [512,128]
        int i = b * 256 + t;
        float s = ((i >> 14) == 2) ? L2E2 : L2E;
        a.dih[l][i] = f2bf(a.wih[l][i] * s);
    } else if (b < 512) {                // w_hh [512,128]
        int i = (b - 256) * 256 + t;
        float s = ((i >> 14) == 2) ? L2E2 : L2E;
        a.dhh[l][i] = f2bf(a.whh[l][i] * s);
    } else if (b < 576) {                // w_l [128,128]
        int i = (b - 512) * 256 + t;
        a.dl[l][i] = f2bf(a.wl[l][i]);
    } else if (b < 640) {                // w_r [128,128]
        int i = (b - 576) * 256 + t;
        a.dr[l][i] = f2bf(a.wr[l][i]);
    } else {                             // combined scaled bias [512] f32
        int i = (b - 640) * 256 + t;
        float s = ((i >> 7) == 2) ? L2E2 : L2E;
        a.dbias[l][i] = (a.bih[l][i] + a.bhh[l][i]) * s;
    }
}

// ---- phase A (round-2 orientation): Xih tile from htile, interleaved out ---
// xihb layout: [node][dim*4 + gate], 8B per dim (4 gates packed bf16).
__device__ __forceinline__ void phaseA2(const unsigned short (*htile)[136],
        const unsigned short* __restrict__ wih, const float* __restrict__ biasc,
        unsigned short* __restrict__ xihb, int mbase, int cl, int qh, int k8, int wv) {
    bf16x8 a[4];
#pragma unroll
    for (int kt = 0; kt < 4; ++kt)
        a[kt] = *(const bf16x8*)(&htile[cl][kt * 32 + k8]);

#pragma unroll
    for (int nt = 0; nt < 2; ++nt) {
        const int col = wv * 32 + nt * 16 + cl;
        f32x4 acc[4];
#pragma unroll
        for (int g = 0; g < 4; ++g) acc[g] = (f32x4){0.f, 0.f, 0.f, 0.f};
#pragma unroll
        for (int g = 0; g < 4; ++g)
#pragma unroll
            for (int kt = 0; kt < 4; ++kt) {
                bf16x8 b = *(const bf16x8*)(wih + (g * 128 + col) * HDIM + kt * 32 + k8);
                acc[g] = mfma16(a[kt], b, acc[g]);
            }
        float bias[4];
#pragma unroll
        for (int g = 0; g < 4; ++g) bias[g] = biasc[g * 128 + col];
#pragma unroll
        for (int r = 0; r < 4; ++r) {
            unsigned p0 = cvtpk(acc[0][r] + bias[0], acc[1][r] + bias[1]);
            unsigned p1 = cvtpk(acc[2][r] + bias[2], acc[3][r] + bias[3]);
            *(ull*)(xihb + (size_t)(mbase + qh * 4 + r) * GDIM + col * 4) =
                (ull)p0 | ((ull)p1 << 32);
        }
    }
}

// ---- gemmA0: build h0 = concat(x, emb[type]) (bf16) + Xih layer 0 ----------
__global__ __launch_bounds__(256) void gemmA0_kernel(
        const float* __restrict__ x, const int* __restrict__ types,
        const float* __restrict__ emb, const unsigned short* __restrict__ wih,
        const float* __restrict__ biasc, unsigned short* __restrict__ h0,
        unsigned short* __restrict__ xihb) {
    __shared__ unsigned short htile[16][136];
    const int lane = threadIdx.x & 63, wv = threadIdx.x >> 6;
    const int cl = lane & 15, qh = lane >> 4, k8 = qh * 8;
    const int mbase = blockIdx.x * 16;

    const int row = threadIdx.x >> 4, c0 = (threadIdx.x & 15) * 8;
    f32x4 u0, u1;
    if (c0 < 96) {
        u0 = *(const f32x4*)(x + (size_t)(mbase + row) * 96 + c0);
        u1 = *(const f32x4*)(x + (size_t)(mbase + row) * 96 + c0 + 4);
    } else {
        int ty = types[mbase + row];
        u0 = *(const f32x4*)(emb + ty * 32 + (c0 - 96));
        u1 = *(const f32x4*)(emb + ty * 32 + (c0 - 96) + 4);
    }
    u32x2 pa, pb;
    pa[0] = cvtpk(u0[0], u0[1]); pa[1] = cvtpk(u0[2], u0[3]);
    pb[0] = cvtpk(u1[0], u1[1]); pb[1] = cvtpk(u1[2], u1[3]);
    *(u32x2*)(&htile[row][c0]) = pa;
    *(u32x2*)(&htile[row][c0 + 4]) = pb;
    *(u32x2*)(h0 + (size_t)(mbase + row) * HDIM + c0) = pa;
    *(u32x2*)(h0 + (size_t)(mbase + row) * HDIM + c0 + 4) = pb;
    __syncthreads();

    phaseA2(htile, wih, biasc, xihb, mbase, cl, qh, k8, wv);
}

// ---------------- fused per-node LSTM (round-2 layout) ----------------------
// 512 threads / 8 waves, 16 nodes per block. Thread owns dim colb=wv*16+cl of
// nodes qh*4..+3; per edge-row one contiguous 8B read (4 gates of one dim).
__global__ __launch_bounds__(512, 4) void lstm_kernel(
        const unsigned short* __restrict__ xihb, const unsigned short* __restrict__ whh,
        const int* __restrict__ esrc, unsigned short* __restrict__ agg) {
    __shared__ unsigned short hbuf[2][16][136];   // +8 pad
    __shared__ unsigned srcs_t[256];              // [t][node], pre-shifted <<10

    const int tid = threadIdx.x;
    const int lane = tid & 63, wv = tid >> 6;
    const int cl = lane & 15, qh = lane >> 4, k8 = qh * 8;
    const int colb = wv * 16 + cl;
    const int base = blockIdx.x * 16;

    if (tid < 256) {
        // esrc index tid = node*16 + t; store transposed [t][node]
        srcs_t[(tid & 15) * 16 + (tid >> 4)] = ((unsigned)esrc[base * DEG + tid]) << 10;
    }

    bf16x8 bfr[4][4];                             // whh fragments [ktile][gate]
#pragma unroll
    for (int kt = 0; kt < 4; ++kt)
#pragma unroll
        for (int g = 0; g < 4; ++g)
            bfr[kt][g] = *(const bf16x8*)(whh + (g * 128 + colb) * HDIM + kt * 32 + k8);
    __syncthreads();

    const char* xb = (const char*)xihb;
    const unsigned coloff = (unsigned)colb * 8u;
    float c[4] = {};
    ull xA[4], xB[4];
    unsigned pk0 = 0, pk1 = 0;

    auto gath = [&](int t, ull* xr) {
        u32x4 sv = *(const u32x4*)&srcs_t[t * 16 + qh * 4];
        xr[0] = *(const ull*)(xb + (sv[0] | coloff));
        xr[1] = *(const ull*)(xb + (sv[1] | coloff));
        xr[2] = *(const ull*)(xb + (sv[2] | coloff));
        xr[3] = *(const ull*)(xb + (sv[3] | coloff));
    };
    gath(0, xA);
    gath(1, xB);

    auto step = [&](int t, ull* xu) {
        f32x4 acc[4];
#pragma unroll
        for (int r = 0; r < 4; ++r) {
            unsigned lo = (unsigned)xu[r], hi = (unsigned)(xu[r] >> 32);
            acc[0][r] = bflo(lo); acc[1][r] = bfhi(lo);
            acc[2][r] = bflo(hi); acc[3][r] = bfhi(hi);
        }
        if (t < 14) gath(t + 2, xu);              // depth-2 prefetch
        if (t > 0) {
            const int rb = (t + 1) & 1;
            bf16x8 a[4];
#pragma unroll
            for (int kt = 0; kt < 4; ++kt)
                a[kt] = *(const bf16x8*)(&hbuf[rb][cl][kt * 32 + k8]);
#pragma unroll
            for (int g = 0; g < 4; ++g)
#pragma unroll
                for (int kt = 0; kt < 4; ++kt)
                    acc[g] = mfma16(a[kt], bfr[kt][g], acc[g]);
        }
        float hv[4];
#pragma unroll
        for (int r = 0; r < 4; ++r) {
            float is = sig_pre(acc[0][r]);
            float fs = sig_pre(acc[1][r]);
            float gt = tanh_pre2(acc[2][r]);
            float os = sig_pre(acc[3][r]);
            float cc = fs * c[r] + is * gt;
            c[r] = cc;
            hv[r] = os * tanh_pre2(cc * L2E2);
        }
        pk0 = cvtpk(hv[0], hv[1]);
        pk1 = cvtpk(hv[2], hv[3]);
        unsigned short* hp = &hbuf[t & 1][qh * 4][colb];
        hp[0]       = (unsigned short)pk0;
        hp[136]     = (unsigned short)(pk0 >> 16);
        hp[272]     = (unsigned short)pk1;
        hp[408]     = (unsigned short)(pk1 >> 16);
        barrier_lgkm();
    };

#pragma unroll
    for (int tt = 0; tt < 8; ++tt) { step(2 * tt, xA); step(2 * tt + 1, xB); }

    unsigned short* ap = agg + (size_t)(base + qh * 4) * HDIM + colb;
    ap[0]   = (unsigned short)pk0;
    ap[128] = (unsigned short)(pk0 >> 16);
    ap[256] = (unsigned short)pk1;
    ap[384] = (unsigned short)(pk1 >> 16);
}

// ---- gemmCA: h_next = relu(agg.wl^T + h.wr^T + bl), then Xih next layer ----
__global__ __launch_bounds__(256) void gemmCA_kernel(
        const unsigned short* __restrict__ agg, const unsigned short* __restrict__ hcur,
        const unsigned short* __restrict__ wl, const unsigned short* __restrict__ wr,
        const float* __restrict__ bl, const unsigned short* __restrict__ wih,
        const float* __restrict__ biasc, unsigned short* __restrict__ hnext,
        unsigned short* __restrict__ xihb) {
    __shared__ unsigned short htile[16][136];
    const int lane = threadIdx.x & 63, wv = threadIdx.x >> 6;
    const int cl = lane & 15, qh = lane >> 4, k8 = qh * 8;
    const int mbase = blockIdx.x * 16;

    bf16x8 bA[4], bH[4];
#pragma unroll
    for (int kt = 0; kt < 4; ++kt) {
        bA[kt] = *(const bf16x8*)(agg  + (size_t)(mbase + cl) * HDIM + kt * 32 + k8);
        bH[kt] = *(const bf16x8*)(hcur + (size_t)(mbase + cl) * HDIM + kt * 32 + k8);
    }
#pragma unroll
    for (int nt = 0; nt < 2; ++nt) {
        const int col = wv * 32 + nt * 16 + cl;
        f32x4 acc = {0.f, 0.f, 0.f, 0.f};
#pragma unroll
        for (int kt = 0; kt < 4; ++kt)
            acc = mfma16(bA[kt], *(const bf16x8*)(wl + col * HDIM + kt * 32 + k8), acc);
#pragma unroll
        for (int kt = 0; kt < 4; ++kt)
            acc = mfma16(bH[kt], *(const bf16x8*)(wr + col * HDIM + kt * 32 + k8), acc);
        float bias = bl[col];
#pragma unroll
        for (int r = 0; r < 4; ++r) {
            unsigned short v = f2bf(fmaxf(acc[r] + bias, 0.f));
            hnext[(size_t)(mbase + qh * 4 + r) * HDIM + col] = v;
            htile[qh * 4 + r][col] = v;
        }
    }
    __syncthreads();

    phaseA2(htile, wih, biasc, xihb, mbase, cl, qh, k8, wv);
}

// ---- gemmCF: out = agg.wl^T + h.wr^T + bl (f32) ----------------------------
__global__ __launch_bounds__(256) void gemmCF_kernel(
        const unsigned short* __restrict__ agg, const unsigned short* __restrict__ hcur,
        const unsigned short* __restrict__ wl, const unsigned short* __restrict__ wr,
        const float* __restrict__ bl, float* __restrict__ fout) {
    const int lane = threadIdx.x & 63, wv = threadIdx.x >> 6;
    const int cl = lane & 15, qh = lane >> 4, k8 = qh * 8;
    const int mbase = blockIdx.x * 16;

    bf16x8 bA[4], bH[4];
#pragma unroll
    for (int kt = 0; kt < 4; ++kt) {
        bA[kt] = *(const bf16x8*)(agg  + (size_t)(mbase + cl) * HDIM + kt * 32 + k8);
        bH[kt] = *(const bf16x8*)(hcur + (size_t)(mbase + cl) * HDIM + kt * 32 + k8);
    }
#pragma unroll
    for (int nt = 0; nt < 2; ++nt) {
        const int col = wv * 32 + nt * 16 + cl;
        f32x4 acc = {0.f, 0.f, 0.f, 0.f};
#pragma unroll
        for (int kt = 0; kt < 4; ++kt)
            acc = mfma16(bA[kt], *(const bf16x8*)(wl + col * HDIM + kt * 32 + k8), acc);
#pragma unroll
        for (int kt = 0; kt < 4; ++kt)
            acc = mfma16(bH[kt], *(const bf16x8*)(wr + col * HDIM + kt * 32 + k8), acc);
        float bias = bl[col];
#pragma unroll
        for (int r = 0; r < 4; ++r)
            fout[(size_t)(mbase + qh * 4 + r) * HDIM + col] = acc[r] + bias;
    }
}

// ---------------- host ------------------------------------------------------
extern "C" void kernel_launch(void* const* d_in, const int* in_sizes, int n_in,
                              void* d_out, int out_size, void* d_ws, size_t ws_size,
                              hipStream_t stream) {
    (void)in_sizes; (void)n_in; (void)out_size; (void)ws_size;

    const float* x     = (const float*)d_in[0];
    const int*   types = (const int*)d_in[1];
    const int*   esrc  = (const int*)d_in[2];
    const float* emb   = (const float*)d_in[4];

    char* ws = (char*)d_ws;
    unsigned short* hA   = (unsigned short*)ws; ws += (size_t)NN * HDIM * 2;
    unsigned short* hB   = (unsigned short*)ws; ws += (size_t)NN * HDIM * 2;
    unsigned short* agg  = (unsigned short*)ws; ws += (size_t)NN * HDIM * 2;
    unsigned short* xihb = (unsigned short*)ws; ws += (size_t)NN * GDIM * 2;
    unsigned short* wbf  = (unsigned short*)ws; ws += (size_t)3 * 163840 * 2;
    float*          bc   = (float*)ws;          // 3 x 512 f32

    unsigned short *wihb[3], *whhb[3], *wlb[3], *wrb[3];
    float* bcl[3];
    CvtArgs ca;
    for (int l = 0; l < 3; ++l) {
        unsigned short* lb = wbf + (size_t)l * 163840;
        wihb[l] = lb;
        whhb[l] = lb + 65536;
        wlb[l]  = lb + 131072;
        wrb[l]  = lb + 147456;
        bcl[l]  = bc + l * 512;
        ca.wih[l] = (const float*)d_in[5 + 7 * l + 0];
        ca.whh[l] = (const float*)d_in[5 + 7 * l + 1];
        ca.bih[l] = (const float*)d_in[5 + 7 * l + 2];
        ca.bhh[l] = (const float*)d_in[5 + 7 * l + 3];
        ca.wl[l]  = (const float*)d_in[5 + 7 * l + 4];
        ca.wr[l]  = (const float*)d_in[5 + 7 * l + 6];
        ca.dih[l] = wihb[l]; ca.dhh[l] = whhb[l]; ca.dl[l] = wlb[l]; ca.dr[l] = wrb[l];
        ca.dbias[l] = bcl[l];
    }
    cvt_kernel<<<1926, 256, 0, stream>>>(ca);

    gemmA0_kernel<<<NN / 16, 256, 0, stream>>>(x, types, emb, wihb[0], bcl[0], hA, xihb);

    unsigned short* hc = hA;
    unsigned short* hn = hB;
    for (int l = 0; l < 3; ++l) {
        const float* bl = (const float*)d_in[5 + 7 * l + 5];
        lstm_kernel<<<NN / 16, 512, 0, stream>>>(xihb, whhb[l], esrc, agg);
        if (l < 2) {
            gemmCA_kernel<<<NN / 16, 256, 0, stream>>>(
                agg, hc, wlb[l], wrb[l], bl, wihb[l + 1], bcl[l + 1], hn, xihb);
            unsigned short* t = hc; hc = hn; hn = t;
        } else {
            gemmCF_kernel<<<NN / 16, 256, 0, stream>>>(
                agg, hc, wlb[l], wrb[l], bl, (float*)d_out);
        }
    }
}

// Round 5
// 303.516 us; speedup vs baseline: 1.6925x; 1.0754x over previous
//
#include <hip/hip_runtime.h>

#define NN 20000
#define DEG 16
#define HDIM 128
#define GDIM 512

typedef __attribute__((ext_vector_type(8))) short bf16x8;
typedef __attribute__((ext_vector_type(4))) float f32x4;
typedef __attribute__((ext_vector_type(2))) unsigned u32x2;
typedef __attribute__((ext_vector_type(4))) unsigned u32x4;
typedef unsigned long long ull;

#define L2E  1.4426950408889634f
#define L2E2 2.8853900817779268f

__device__ __forceinline__ f32x4 mfma16(bf16x8 a, bf16x8 b, f32x4 c) {
    return __builtin_amdgcn_mfma_f32_16x16x32_bf16(a, b, c, 0, 0, 0);
}

__device__ __forceinline__ unsigned short f2bf(float f) {
    unsigned u = __builtin_bit_cast(unsigned, f);
    u += 0x7FFFu + ((u >> 16) & 1u);
    return (unsigned short)(u >> 16);
}

__device__ __forceinline__ unsigned cvtpk(float lo, float hi) {
    unsigned r;
    asm("v_cvt_pk_bf16_f32 %0, %1, %2" : "=v"(r) : "v"(lo), "v"(hi));
    return r;
}

__device__ __forceinline__ float bfhi(unsigned u) { return __builtin_bit_cast(float, u & 0xFFFF0000u); }
__device__ __forceinline__ float bflo(unsigned u) { return __builtin_bit_cast(float, u << 16); }

__device__ __forceinline__ void barrier_lgkm() {
    asm volatile("s_waitcnt lgkmcnt(0)\ns_barrier" ::: "memory");
}

__device__ __forceinline__ float sig_pre(float x) {     // x pre-scaled by log2e
    return __builtin_amdgcn_rcpf(1.f + __builtin_amdgcn_exp2f(-x));
}
__device__ __forceinline__ float tanh_pre2(float x2) {  // x2 pre-scaled by 2*log2e
    return 1.f - 2.f * __builtin_amdgcn_rcpf(__builtin_amdgcn_exp2f(x2) + 1.f);
}

// ---------------- weight convert + combined bias ----------------------------
struct CvtArgs {
    const float *wih[3], *whh[3], *wl[3], *wr[3], *bih[3], *bhh[3];
    unsigned short *dih[3], *dhh[3], *dl[3], *dr[3];
    float *dbias[3];
};

__global__ __launch_bounds__(256) void cvt_kernel(CvtArgs a) {
    int l = blockIdx.x / 642, b = blockIdx.x % 642, t = threadIdx.x;
    if (b < 256) {
        int i = b * 256 + t;
        float s = ((i >> 14) == 2) ? L2E2 : L2E;
        a.dih[l][i] = f2bf(a.wih[l][i] * s);
    } else if (b < 512) {
        int i = (b - 256) * 256 + t;
        float s = ((i >> 14) == 2) ? L2E2 : L2E;
        a.dhh[l][i] = f2bf(a.whh[l][i] * s);
    } else if (b < 576) {
        int i = (b - 512) * 256 + t;
        a.dl[l][i] = f2bf(a.wl[l][i]);
    } else if (b < 640) {
        int i = (b - 576) * 256 + t;
        a.dr[l][i] = f2bf(a.wr[l][i]);
    } else {
        int i = (b - 640) * 256 + t;
        float s = ((i >> 7) == 2) ? L2E2 : L2E;
        a.dbias[l][i] = (a.bih[l][i] + a.bhh[l][i]) * s;
    }
}

// ---- phase A (32-node tile): Xih from htile, interleaved bf16 out ----------
// xihb layout: [node][dim*4 + gate], 8B per dim (4 gates packed bf16).
__device__ __forceinline__ void phaseA2(const unsigned short (*htile)[136],
        const unsigned short* __restrict__ wih, const float* __restrict__ biasc,
        unsigned short* __restrict__ xihb, int mbase, int cl, int qh, int k8, int wv) {
    bf16x8 a0[4], a1[4];
#pragma unroll
    for (int kt = 0; kt < 4; ++kt) {
        a0[kt] = *(const bf16x8*)(&htile[cl][kt * 32 + k8]);
        a1[kt] = *(const bf16x8*)(&htile[16 + cl][kt * 32 + k8]);
    }
#pragma unroll
    for (int nt = 0; nt < 2; ++nt) {
        const int col = wv * 32 + nt * 16 + cl;
        f32x4 acc0[4], acc1[4];
#pragma unroll
        for (int g = 0; g < 4; ++g) {
            acc0[g] = (f32x4){0.f, 0.f, 0.f, 0.f};
            acc1[g] = (f32x4){0.f, 0.f, 0.f, 0.f};
        }
#pragma unroll
        for (int g = 0; g < 4; ++g)
#pragma unroll
            for (int kt = 0; kt < 4; ++kt) {
                bf16x8 b = *(const bf16x8*)(wih + (g * 128 + col) * HDIM + kt * 32 + k8);
                acc0[g] = mfma16(a0[kt], b, acc0[g]);
                acc1[g] = mfma16(a1[kt], b, acc1[g]);
            }
        float bias[4];
#pragma unroll
        for (int g = 0; g < 4; ++g) bias[g] = biasc[g * 128 + col];
#pragma unroll
        for (int r = 0; r < 4; ++r) {
            unsigned p0 = cvtpk(acc0[0][r] + bias[0], acc0[1][r] + bias[1]);
            unsigned p1 = cvtpk(acc0[2][r] + bias[2], acc0[3][r] + bias[3]);
            *(ull*)(xihb + (size_t)(mbase + qh * 4 + r) * GDIM + col * 4) =
                (ull)p0 | ((ull)p1 << 32);
            unsigned q0 = cvtpk(acc1[0][r] + bias[0], acc1[1][r] + bias[1]);
            unsigned q1 = cvtpk(acc1[2][r] + bias[2], acc1[3][r] + bias[3]);
            *(ull*)(xihb + (size_t)(mbase + 16 + qh * 4 + r) * GDIM + col * 4) =
                (ull)q0 | ((ull)q1 << 32);
        }
    }
}

// ---- gemmA0: h0 = concat(x, emb[type]) (bf16) + Xih layer 0, 32 nodes ------
__global__ __launch_bounds__(256) void gemmA0_kernel(
        const float* __restrict__ x, const int* __restrict__ types,
        const float* __restrict__ emb, const unsigned short* __restrict__ wih,
        const float* __restrict__ biasc, unsigned short* __restrict__ h0,
        unsigned short* __restrict__ xihb) {
    __shared__ unsigned short htile[32][136];
    const int tid = threadIdx.x;
    const int lane = tid & 63, wv = tid >> 6;
    const int cl = lane & 15, qh = lane >> 4, k8 = qh * 8;
    const int mbase = blockIdx.x * 32;

    const int row = tid >> 3, c0 = (tid & 7) * 16;
    f32x4 u[4];
    if (c0 < 96) {
#pragma unroll
        for (int j = 0; j < 4; ++j)
            u[j] = *(const f32x4*)(x + (size_t)(mbase + row) * 96 + c0 + 4 * j);
    } else {
        int ty = types[mbase + row];
#pragma unroll
        for (int j = 0; j < 4; ++j)
            u[j] = *(const f32x4*)(emb + ty * 32 + (c0 - 96) + 4 * j);
    }
    u32x4 pk, pk2;
    pk[0]  = cvtpk(u[0][0], u[0][1]); pk[1]  = cvtpk(u[0][2], u[0][3]);
    pk[2]  = cvtpk(u[1][0], u[1][1]); pk[3]  = cvtpk(u[1][2], u[1][3]);
    pk2[0] = cvtpk(u[2][0], u[2][1]); pk2[1] = cvtpk(u[2][2], u[2][3]);
    pk2[2] = cvtpk(u[3][0], u[3][1]); pk2[3] = cvtpk(u[3][2], u[3][3]);
    *(u32x4*)(&htile[row][c0]) = pk;
    *(u32x4*)(&htile[row][c0 + 8]) = pk2;
    *(u32x4*)(h0 + (size_t)(mbase + row) * HDIM + c0) = pk;
    *(u32x4*)(h0 + (size_t)(mbase + row) * HDIM + c0 + 8) = pk2;
    __syncthreads();

    phaseA2(htile, wih, biasc, xihb, mbase, cl, qh, k8, wv);
}

// ---------------- fused per-node LSTM ---------------------------------------
// 512 threads / 8 waves, 16 nodes/block. whh fragments pinned via asm loads.
__global__ __launch_bounds__(512, 4) void lstm_kernel(
        const unsigned short* __restrict__ xihb, const unsigned short* __restrict__ whh,
        const int* __restrict__ esrc, unsigned short* __restrict__ agg) {
    __shared__ unsigned short hbuf[2][16][136];   // +8 pad
    __shared__ unsigned srcs_t[256];              // [t][node], pre-shifted <<10

    const int tid = threadIdx.x;
    const int lane = tid & 63, wv = tid >> 6;
    const int cl = lane & 15, qh = lane >> 4, k8 = qh * 8;
    const int colb = wv * 16 + cl;
    const int base = blockIdx.x * 16;

    if (tid < 256)
        srcs_t[(tid & 15) * 16 + (tid >> 4)] = ((unsigned)esrc[base * DEG + tid]) << 10;

    bf16x8 bfr[4][4];                             // whh fragments, asm-pinned
#pragma unroll
    for (int kt = 0; kt < 4; ++kt)
#pragma unroll
        for (int g = 0; g < 4; ++g)
            asm volatile("global_load_dwordx4 %0, %1, off"
                         : "=v"(bfr[kt][g])
                         : "v"(whh + (g * 128 + colb) * HDIM + kt * 32 + k8));
    asm volatile("s_waitcnt vmcnt(0)" ::: "memory");
    __builtin_amdgcn_sched_barrier(0);
    __syncthreads();

    const char* xb = (const char*)xihb;
    const unsigned coloff = (unsigned)colb * 8u;
    float c[4] = {};
    ull xA[4], xB[4];
    unsigned pk0 = 0, pk1 = 0;

    auto gath = [&](int t, ull* xr) {
        u32x4 sv = *(const u32x4*)&srcs_t[t * 16 + qh * 4];
        xr[0] = *(const ull*)(xb + (sv[0] | coloff));
        xr[1] = *(const ull*)(xb + (sv[1] | coloff));
        xr[2] = *(const ull*)(xb + (sv[2] | coloff));
        xr[3] = *(const ull*)(xb + (sv[3] | coloff));
    };
    gath(0, xA);
    gath(1, xB);

    auto step = [&](int t, ull* xu) {
        f32x4 acc[4];
#pragma unroll
        for (int r = 0; r < 4; ++r) {
            unsigned lo = (unsigned)xu[r], hi = (unsigned)(xu[r] >> 32);
            acc[0][r] = bflo(lo); acc[1][r] = bfhi(lo);
            acc[2][r] = bflo(hi); acc[3][r] = bfhi(hi);
        }
        if (t < 14) gath(t + 2, xu);              // depth-2 prefetch
        if (t > 0) {
            const int rb = (t + 1) & 1;
            bf16x8 a[4];
#pragma unroll
            for (int kt = 0; kt < 4; ++kt)
                a[kt] = *(const bf16x8*)(&hbuf[rb][cl][kt * 32 + k8]);
#pragma unroll
            for (int g = 0; g < 4; ++g)
#pragma unroll
                for (int kt = 0; kt < 4; ++kt)
                    acc[g] = mfma16(a[kt], bfr[kt][g], acc[g]);
        }
        float hv[4];
#pragma unroll
        for (int r = 0; r < 4; ++r) {
            float is = sig_pre(acc[0][r]);
            float fs = sig_pre(acc[1][r]);
            float gt = tanh_pre2(acc[2][r]);
            float os = sig_pre(acc[3][r]);
            float cc = fs * c[r] + is * gt;
            c[r] = cc;
            hv[r] = os * tanh_pre2(cc * L2E2);
        }
        pk0 = cvtpk(hv[0], hv[1]);
        pk1 = cvtpk(hv[2], hv[3]);
        unsigned short* hp = &hbuf[t & 1][qh * 4][colb];
        hp[0]   = (unsigned short)pk0;
        hp[136] = (unsigned short)(pk0 >> 16);
        hp[272] = (unsigned short)pk1;
        hp[408] = (unsigned short)(pk1 >> 16);
        barrier_lgkm();
    };

#pragma unroll
    for (int tt = 0; tt < 8; ++tt) { step(2 * tt, xA); step(2 * tt + 1, xB); }

    unsigned short* ap = agg + (size_t)(base + qh * 4) * HDIM + colb;
    ap[0]   = (unsigned short)pk0;
    ap[128] = (unsigned short)(pk0 >> 16);
    ap[256] = (unsigned short)pk1;
    ap[384] = (unsigned short)(pk1 >> 16);
}

// ---- gemmCA: h_next = relu(agg.wl^T + h.wr^T + bl) + Xih next, 32 nodes ----
__global__ __launch_bounds__(256) void gemmCA_kernel(
        const unsigned short* __restrict__ agg, const unsigned short* __restrict__ hcur,
        const unsigned short* __restrict__ wl, const unsigned short* __restrict__ wr,
        const float* __restrict__ bl, const unsigned short* __restrict__ wih,
        const float* __restrict__ biasc, unsigned short* __restrict__ hnext,
        unsigned short* __restrict__ xihb) {
    __shared__ unsigned short htile[32][136];
    const int lane = threadIdx.x & 63, wv = threadIdx.x >> 6;
    const int cl = lane & 15, qh = lane >> 4, k8 = qh * 8;
    const int mbase = blockIdx.x * 32;

    bf16x8 bA0[4], bA1[4], bH0[4], bH1[4];
#pragma unroll
    for (int kt = 0; kt < 4; ++kt) {
        bA0[kt] = *(const bf16x8*)(agg  + (size_t)(mbase + cl) * HDIM + kt * 32 + k8);
        bA1[kt] = *(const bf16x8*)(agg  + (size_t)(mbase + 16 + cl) * HDIM + kt * 32 + k8);
        bH0[kt] = *(const bf16x8*)(hcur + (size_t)(mbase + cl) * HDIM + kt * 32 + k8);
        bH1[kt] = *(const bf16x8*)(hcur + (size_t)(mbase + 16 + cl) * HDIM + kt * 32 + k8);
    }
#pragma unroll
    for (int nt = 0; nt < 2; ++nt) {
        const int col = wv * 32 + nt * 16 + cl;
        f32x4 acc0 = {0.f, 0.f, 0.f, 0.f}, acc1 = {0.f, 0.f, 0.f, 0.f};
#pragma unroll
        for (int kt = 0; kt < 4; ++kt) {
            bf16x8 w = *(const bf16x8*)(wl + col * HDIM + kt * 32 + k8);
            acc0 = mfma16(bA0[kt], w, acc0);
            acc1 = mfma16(bA1[kt], w, acc1);
        }
#pragma unroll
        for (int kt = 0; kt < 4; ++kt) {
            bf16x8 w = *(const bf16x8*)(wr + col * HDIM + kt * 32 + k8);
            acc0 = mfma16(bH0[kt], w, acc0);
            acc1 = mfma16(bH1[kt], w, acc1);
        }
        float bias = bl[col];
#pragma unroll
        for (int r = 0; r < 4; ++r) {
            unsigned short v0 = f2bf(fmaxf(acc0[r] + bias, 0.f));
            unsigned short v1 = f2bf(fmaxf(acc1[r] + bias, 0.f));
            hnext[(size_t)(mbase + qh * 4 + r) * HDIM + col] = v0;
            hnext[(size_t)(mbase + 16 + qh * 4 + r) * HDIM + col] = v1;
            htile[qh * 4 + r][col] = v0;
            htile[16 + qh * 4 + r][col] = v1;
        }
    }
    __syncthreads();

    phaseA2(htile, wih, biasc, xihb, mbase, cl, qh, k8, wv);
}

// ---- gemmCF: out = agg.wl^T + h.wr^T + bl (f32), 32 nodes ------------------
__global__ __launch_bounds__(256) void gemmCF_kernel(
        const unsigned short* __restrict__ agg, const unsigned short* __restrict__ hcur,
        const unsigned short* __restrict__ wl, const unsigned short* __restrict__ wr,
        const float* __restrict__ bl, float* __restrict__ fout) {
    const int lane = threadIdx.x & 63, wv = threadIdx.x >> 6;
    const int cl = lane & 15, qh = lane >> 4, k8 = qh * 8;
    const int mbase = blockIdx.x * 32;

    bf16x8 bA0[4], bA1[4], bH0[4], bH1[4];
#pragma unroll
    for (int kt = 0; kt < 4; ++kt) {
        bA0[kt] = *(const bf16x8*)(agg  + (size_t)(mbase + cl) * HDIM + kt * 32 + k8);
        bA1[kt] = *(const bf16x8*)(agg  + (size_t)(mbase + 16 + cl) * HDIM + kt * 32 + k8);
        bH0[kt] = *(const bf16x8*)(hcur + (size_t)(mbase + cl) * HDIM + kt * 32 + k8);
        bH1[kt] = *(const bf16x8*)(hcur + (size_t)(mbase + 16 + cl) * HDIM + kt * 32 + k8);
    }
#pragma unroll
    for (int nt = 0; nt < 2; ++nt) {
        const int col = wv * 32 + nt * 16 + cl;
        f32x4 acc0 = {0.f, 0.f, 0.f, 0.f}, acc1 = {0.f, 0.f, 0.f, 0.f};
#pragma unroll
        for (int kt = 0; kt < 4; ++kt) {
            bf16x8 w = *(const bf16x8*)(wl + col * HDIM + kt * 32 + k8);
            acc0 = mfma16(bA0[kt], w, acc0);
            acc1 = mfma16(bA1[kt], w, acc1);
        }
#pragma unroll
        for (int kt = 0; kt < 4; ++kt) {
            bf16x8 w = *(const bf16x8*)(wr + col * HDIM + kt * 32 + k8);
            acc0 = mfma16(bH0[kt], w, acc0);
            acc1 = mfma16(bH1[kt], w, acc1);
        }
        float bias = bl[col];
#pragma unroll
        for (int r = 0; r < 4; ++r) {
            fout[(size_t)(mbase + qh * 4 + r) * HDIM + col] = acc0[r] + bias;
            fout[(size_t)(mbase + 16 + qh * 4 + r) * HDIM + col] = acc1[r] + bias;
        }
    }
}

// ---------------- host ------------------------------------------------------
extern "C" void kernel_launch(void* const* d_in, const int* in_sizes, int n_in,
                              void* d_out, int out_size, void* d_ws, size_t ws_size,
                              hipStream_t stream) {
    (void)in_sizes; (void)n_in; (void)out_size; (void)ws_size;

    const float* x     = (const float*)d_in[0];
    const int*   types = (const int*)d_in[1];
    const int*   esrc  = (const int*)d_in[2];
    const float* emb   = (const float*)d_in[4];

    char* ws = (char*)d_ws;
    unsigned short* hA   = (unsigned short*)ws; ws += (size_t)NN * HDIM * 2;
    unsigned short* hB   = (unsigned short*)ws; ws += (size_t)NN * HDIM * 2;
    unsigned short* agg  = (unsigned short*)ws; ws += (size_t)NN * HDIM * 2;
    unsigned short* xihb = (unsigned short*)ws; ws += (size_t)NN * GDIM * 2;
    unsigned short* wbf  = (unsigned short*)ws; ws += (size_t)3 * 163840 * 2;
    float*          bc   = (float*)ws;          // 3 x 512 f32

    unsigned short *wihb[3], *whhb[3], *wlb[3], *wrb[3];
    float* bcl[3];
    CvtArgs ca;
    for (int l = 0; l < 3; ++l) {
        unsigned short* lb = wbf + (size_t)l * 163840;
        wihb[l] = lb;
        whhb[l] = lb + 65536;
        wlb[l]  = lb + 131072;
        wrb[l]  = lb + 147456;
        bcl[l]  = bc + l * 512;
        ca.wih[l] = (const float*)d_in[5 + 7 * l + 0];
        ca.whh[l] = (const float*)d_in[5 + 7 * l + 1];
        ca.bih[l] = (const float*)d_in[5 + 7 * l + 2];
        ca.bhh[l] = (const float*)d_in[5 + 7 * l + 3];
        ca.wl[l]  = (const float*)d_in[5 + 7 * l + 4];
        ca.wr[l]  = (const float*)d_in[5 + 7 * l + 6];
        ca.dih[l] = wihb[l]; ca.dhh[l] = whhb[l]; ca.dl[l] = wlb[l]; ca.dr[l] = wrb[l];
        ca.dbias[l] = bcl[l];
    }
    cvt_kernel<<<1926, 256, 0, stream>>>(ca);

    gemmA0_kernel<<<NN / 32, 256, 0, stream>>>(x, types, emb, wihb[0], bcl[0], hA, xihb);

    unsigned short* hc = hA;
    unsigned short* hn = hB;
    for (int l = 0; l < 3; ++l) {
        const float* bl = (const float*)d_in[5 + 7 * l + 5];
        lstm_kernel<<<NN / 16, 512, 0, stream>>>(xihb, whhb[l], esrc, agg);
        if (l < 2) {
            gemmCA_kernel<<<NN / 32, 256, 0, stream>>>(
                agg, hc, wlb[l], wrb[l], bl, wihb[l + 1], bcl[l + 1], hn, xihb);
            unsigned short* t = hc; hc = hn; hn = t;
        } else {
            gemmCF_kernel<<<NN / 32, 256, 0, stream>>>(
                agg, hc, wlb[l], wrb[l], bl, (float*)d_out);
        }
    }
}